// Round 1
// baseline (490.746 us; speedup 1.0000x reference)
//
#include <hip/hip_runtime.h>

// ---- ArcFace constants ----
#define S_SCALE 30.0f
#define COS_M 0.8775825618903728f
#define SIN_M 0.479425538604203f
#define TH_C (-0.8775825618903728f)
#define MM_C 0.2397127693021015f

#define BD 512      // 2B rows
#define DD 512      // feature dim
#define CC 100000   // classes
#define NCB 3125    // 100000 / 32 column blocks

typedef __bf16 bf16x8 __attribute__((ext_vector_type(8)));
typedef __bf16 bf16x4 __attribute__((ext_vector_type(4)));
typedef float  f32x4  __attribute__((ext_vector_type(4)));

// ---------------- Kernel 1: concat + row-normalize emb -> bf16 A [512][512] ----------------
__global__ __launch_bounds__(256) void k_norm_emb(const float* __restrict__ img,
                                                  const float* __restrict__ prof,
                                                  __bf16* __restrict__ A) {
    const int row = blockIdx.x;
    const int t = threadIdx.x;
    const float* src = (row < 256) ? (img + (size_t)row * DD) : (prof + (size_t)(row - 256) * DD);
    float x0 = src[t], x1 = src[t + 256];
    float s = x0 * x0 + x1 * x1;
    for (int o = 1; o < 64; o <<= 1) s += __shfl_xor(s, o);
    __shared__ float ws4[4];
    if ((t & 63) == 0) ws4[t >> 6] = s;
    __syncthreads();
    float r = rsqrtf(ws4[0] + ws4[1] + ws4[2] + ws4[3]);
    A[(size_t)row * DD + t]       = (__bf16)(x0 * r);
    A[(size_t)row * DD + t + 256] = (__bf16)(x1 * r);
}

// ---------------- Kernel 2: label-column cosine + phi (fp32 accum of bf16-truncated vals) ----
__global__ __launch_bounds__(256) void k_label(const __bf16* __restrict__ A,
                                               const float* __restrict__ W,
                                               const int* __restrict__ lab,
                                               float* __restrict__ sphi,
                                               float* __restrict__ scos) {
    const int n = blockIdx.x;
    const int t = threadIdx.x;
    const int c = lab[n & 255];
    const float* wr = W + (size_t)c * DD;
    float dot = 0.f, wsq = 0.f;
    for (int idx = t; idx < DD; idx += 256) {
        float wv = (float)(__bf16)wr[idx];   // truncate like the GEMM does
        float av = (float)A[(size_t)n * DD + idx];
        dot += av * wv;
        wsq += wv * wv;
    }
    for (int o = 1; o < 64; o <<= 1) { dot += __shfl_xor(dot, o); wsq += __shfl_xor(wsq, o); }
    __shared__ float sd[4], sw[4];
    if ((t & 63) == 0) { sd[t >> 6] = dot; sw[t >> 6] = wsq; }
    __syncthreads();
    if (t == 0) {
        float D = sd[0] + sd[1] + sd[2] + sd[3];
        float Q = sw[0] + sw[1] + sw[2] + sw[3];
        float cs = D * rsqrtf(Q);
        float sn = sqrtf(fmaxf(0.f, fminf(1.f, 1.f - cs * cs)));
        float phi = cs * COS_M - sn * SIN_M;
        if (!(cs > TH_C)) phi = cs - MM_C;
        sphi[n] = S_SCALE * phi;
        scos[n] = S_SCALE * cs;
    }
}

// ---------------- Kernel 3: MFMA GEMM + fused partial sum-exp ----------------
// Block: 256 thr = 4 waves. Each block: 32 weight cols x all 512 rows, K=512 in 16 tiles of 32.
// Weight norms accumulated from bf16-truncated values during staging; applied in epilogue.
__global__ __launch_bounds__(256) void k_gemm_partial(const __bf16* __restrict__ A,
                                                      const float* __restrict__ W,
                                                      float* __restrict__ part) {
    __shared__ __bf16 As[BD * 32];   // [row][32k]  32 KB
    __shared__ __bf16 Bs[32 * 32];   // [col][32k]   2 KB
    __shared__ float  csq[32];

    const int t = threadIdx.x;
    const int cb = blockIdx.x;
    const int wave = t >> 6, lane = t & 63;
    const int q = lane >> 4, m16 = lane & 15;

    // B staging mapping: thread t -> col t>>3, k-chunk (t&7)*4
    const int bcol = t >> 3, bsub = t & 7;
    const float* wptr = W + (size_t)(cb * 32 + bcol) * DD + bsub * 4;

    f32x4 acc[8][2] = {};
    float sq = 0.f;

    for (int kt = 0; kt < 16; ++kt) {
        // A stage: 512 rows x 32 k of bf16 = 32 KB, 8 iters x 256 thr x 16 B, coalesced
        #pragma unroll
        for (int it = 0; it < 8; ++it) {
            int j = it * 256 + t;
            int row = j >> 2, ch = j & 3;
            int4 v = *(const int4*)(A + (size_t)row * DD + kt * 32 + ch * 8);
            *(int4*)(As + j * 8) = v;
        }
        // B stage: 4 fp32 -> bf16, accumulate sumsq of truncated values
        float4 wv4 = *(const float4*)(wptr + kt * 32);
        bf16x4 bv = { (__bf16)wv4.x, (__bf16)wv4.y, (__bf16)wv4.z, (__bf16)wv4.w };
        float f0 = (float)bv[0], f1 = (float)bv[1], f2 = (float)bv[2], f3 = (float)bv[3];
        sq += f0 * f0 + f1 * f1 + f2 * f2 + f3 * f3;
        *(bf16x4*)(Bs + bcol * 32 + bsub * 4) = bv;
        __syncthreads();

        bf16x8 bf0 = *(const bf16x8*)(Bs + (m16) * 32 + q * 8);
        bf16x8 bf1 = *(const bf16x8*)(Bs + (16 + m16) * 32 + q * 8);
        #pragma unroll
        for (int i = 0; i < 8; ++i) {
            bf16x8 af = *(const bf16x8*)(As + (size_t)(wave * 128 + i * 16 + m16) * 32 + q * 8);
            acc[i][0] = __builtin_amdgcn_mfma_f32_16x16x32_bf16(af, bf0, acc[i][0], 0, 0, 0);
            acc[i][1] = __builtin_amdgcn_mfma_f32_16x16x32_bf16(af, bf1, acc[i][1], 0, 0, 0);
        }
        __syncthreads();
    }

    // column sumsq: reduce across 8 threads sharing a column (lane bits 0..2)
    sq += __shfl_xor(sq, 1);
    sq += __shfl_xor(sq, 2);
    sq += __shfl_xor(sq, 4);
    if (bsub == 0) csq[bcol] = sq;
    __syncthreads();

    // epilogue: cosine = acc * rsqrt(csq[col]); partial[row] = sum_c exp(S*cosine)
    const float inv0 = rsqrtf(csq[m16]) * S_SCALE;
    const float inv1 = rsqrtf(csq[16 + m16]) * S_SCALE;
    #pragma unroll
    for (int i = 0; i < 8; ++i) {
        #pragma unroll
        for (int r = 0; r < 4; ++r) {
            float e = __expf(acc[i][0][r] * inv0) + __expf(acc[i][1][r] * inv1);
            e += __shfl_xor(e, 1);
            e += __shfl_xor(e, 2);
            e += __shfl_xor(e, 4);
            e += __shfl_xor(e, 8);
            if (m16 == 0) {
                int row = wave * 128 + i * 16 + q * 4 + r;
                part[(size_t)row * NCB + cb] = e;
            }
        }
    }
}

// ---------------- Kernel 4: per-row total sum-exp -> LSE, label correction, nll ------------
__global__ __launch_bounds__(256) void k_reduce(const float* __restrict__ part,
                                                const float* __restrict__ sphi,
                                                const float* __restrict__ scos,
                                                float* __restrict__ nll) {
    const int row = blockIdx.x;
    const int t = threadIdx.x;
    const float* p = part + (size_t)row * NCB;
    float s = 0.f;
    for (int j = t; j < NCB; j += 256) s += p[j];
    for (int o = 1; o < 64; o <<= 1) s += __shfl_xor(s, o);
    __shared__ float ws4[4];
    if ((t & 63) == 0) ws4[t >> 6] = s;
    __syncthreads();
    if (t == 0) {
        float total = ws4[0] + ws4[1] + ws4[2] + ws4[3];
        float lse = logf(total);
        float sp = sphi[row], sc = scos[row];
        // replace label's cos-term with phi-term inside the logsumexp
        float corr = log1pf(__expf(sp - lse) - __expf(sc - lse));
        nll[row] = lse + corr - sp;
    }
}

// ---------------- Kernel 5: mean over 512 rows ----------------
__global__ __launch_bounds__(256) void k_mean(const float* __restrict__ nll, float* __restrict__ out) {
    const int t = threadIdx.x;
    float s = nll[t] + nll[t + 256];
    for (int o = 1; o < 64; o <<= 1) s += __shfl_xor(s, o);
    __shared__ float ws4[4];
    if ((t & 63) == 0) ws4[t >> 6] = s;
    __syncthreads();
    if (t == 0) out[0] = (ws4[0] + ws4[1] + ws4[2] + ws4[3]) * (1.0f / 512.0f);
}

extern "C" void kernel_launch(void* const* d_in, const int* in_sizes, int n_in,
                              void* d_out, int out_size, void* d_ws, size_t ws_size,
                              hipStream_t stream) {
    const float* img  = (const float*)d_in[0];
    const float* prof = (const float*)d_in[1];
    const float* W    = (const float*)d_in[2];
    const int*   lab  = (const int*)d_in[3];

    char* ws = (char*)d_ws;
    __bf16* A    = (__bf16*)ws;                 // 512*512*2 = 524288 B
    float* sphi  = (float*)(ws + 524288);       // 2048 B
    float* scos  = (float*)(ws + 526336);       // 2048 B
    float* nll   = (float*)(ws + 528384);       // 2048 B
    float* part  = (float*)(ws + 530432);       // 512*3125*4 = 6,400,000 B

    k_norm_emb<<<BD, 256, 0, stream>>>(img, prof, A);
    k_label<<<BD, 256, 0, stream>>>(A, W, lab, sphi, scos);
    k_gemm_partial<<<NCB, 256, 0, stream>>>(A, W, part);
    k_reduce<<<BD, 256, 0, stream>>>(part, sphi, scos, nll);
    k_mean<<<1, 256, 0, stream>>>(nll, (float*)d_out);
}

// Round 2
// 445.474 us; speedup vs baseline: 1.1016x; 1.1016x over previous
//
#include <hip/hip_runtime.h>

#define S_SCALE 30.0f
#define COS_M 0.8775825618903728f
#define SIN_M 0.479425538604203f
#define TH_C (-0.8775825618903728f)
#define MM_C 0.2397127693021015f

#define BD 512
#define DD 512
#define CC 100000
#define NCB 1563            // ceil(100000/64)
#define LASTB 1562

typedef __bf16 bf16x8 __attribute__((ext_vector_type(8)));
typedef __bf16 bf16x4 __attribute__((ext_vector_type(4)));
typedef float  f32x4  __attribute__((ext_vector_type(4)));

#define AS1 __attribute__((address_space(1)))
#define AS3 __attribute__((address_space(3)))

// ---------------- Kernel 1: concat + normalize -> k-tiled bf16 A_t[16][512][32];
// also label-column cosine/phi, and zero d_out for the atomic mean. ----------------
__global__ __launch_bounds__(256) void k_prep(const float* __restrict__ img,
                                              const float* __restrict__ prof,
                                              const float* __restrict__ W,
                                              const int* __restrict__ lab,
                                              __bf16* __restrict__ At,
                                              float* __restrict__ sphi,
                                              float* __restrict__ scos,
                                              float* __restrict__ out) {
    const int row = blockIdx.x;
    const int t = threadIdx.x;
    const float* src = (row < 256) ? (img + (size_t)row * DD) : (prof + (size_t)(row - 256) * DD);
    float x0 = src[t], x1 = src[t + 256];
    float s = x0 * x0 + x1 * x1;
    for (int o = 1; o < 64; o <<= 1) s += __shfl_xor(s, o);
    __shared__ float ws4[4];
    if ((t & 63) == 0) ws4[t >> 6] = s;
    __syncthreads();
    float r = rsqrtf(ws4[0] + ws4[1] + ws4[2] + ws4[3]);
    __bf16 a0 = (__bf16)(x0 * r), a1 = (__bf16)(x1 * r);
    // k-tiled layout: element (row, d) -> At[(d>>5)*16384 + row*32 + (d&31)]
    At[(size_t)(t >> 5) * (BD * 32) + row * 32 + (t & 31)]           = a0;
    At[(size_t)((t + 256) >> 5) * (BD * 32) + row * 32 + (t & 31)]   = a1;

    // label-column cosine (on bf16-truncated values, matching the GEMM)
    const int c = lab[row & 255];
    float w0 = (float)(__bf16)W[(size_t)c * DD + t];
    float w1 = (float)(__bf16)W[(size_t)c * DD + t + 256];
    float dot = (float)a0 * w0 + (float)a1 * w1;
    float wsq = w0 * w0 + w1 * w1;
    for (int o = 1; o < 64; o <<= 1) { dot += __shfl_xor(dot, o); wsq += __shfl_xor(wsq, o); }
    __shared__ float sd[4], sw[4];
    if ((t & 63) == 0) { sd[t >> 6] = dot; sw[t >> 6] = wsq; }
    __syncthreads();
    if (t == 0) {
        float D = sd[0] + sd[1] + sd[2] + sd[3];
        float Q = sw[0] + sw[1] + sw[2] + sw[3];
        float cs = D * rsqrtf(Q);
        float sn = sqrtf(fmaxf(0.f, fminf(1.f, 1.f - cs * cs)));
        float phi = cs * COS_M - sn * SIN_M;
        if (!(cs > TH_C)) phi = cs - MM_C;
        sphi[row] = S_SCALE * phi;
        scos[row] = S_SCALE * cs;
        if (row == 0) out[0] = 0.f;
    }
}

// ---------------- Kernel 2: MFMA GEMM, 512 rows x 64 cols per block ----------------
// Double-buffered LDS, one barrier/tile, A via global_load_lds (16B), W prefetched in regs.
__global__ __launch_bounds__(256, 2) void k_gemm(const __bf16* __restrict__ At,
                                                 const float* __restrict__ W,
                                                 float* __restrict__ part) {
    __shared__ __bf16 As[2][BD * 32];    // 2 x 32 KB
    __shared__ __bf16 Bs[2][64 * 32];    // 2 x 4 KB
    __shared__ float  csq[64];

    const int t = threadIdx.x;
    const int cb = blockIdx.x;
    const int wave = t >> 6, lane = t & 63, q = lane >> 4, m16 = lane & 15;

    // W staging: thread t covers (col t>>3, kc t&7) and (col 32+(t>>3), kc t&7)
    const int wcol = t >> 3, kc = t & 7;
    int gc0 = cb * 64 + wcol;
    int gc1 = gc0 + 32;
    const float* wp0 = W + (size_t)(gc0 < CC ? gc0 : 0) * DD + kc * 4;
    const float* wp1 = W + (size_t)(gc1 < CC ? gc1 : 0) * DD + kc * 4;

    f32x4 acc[8][4] = {};
    float sq0 = 0.f, sq1 = 0.f;

#define GLDS_TILE(kt, buf)                                                              \
    {                                                                                   \
        const char* gsrc = (const char*)At + (size_t)(kt) * 32768;                      \
        _Pragma("unroll")                                                               \
        for (int c8 = 0; c8 < 8; ++c8) {                                                \
            __builtin_amdgcn_global_load_lds(                                           \
                (AS1 void*)(gsrc + (c8 * 256 + t) * 16),                                \
                (AS3 void*)((char*)(&As[buf][0]) + (c8 * 256 + wave * 64) * 16),        \
                16, 0, 0);                                                              \
        }                                                                               \
    }

#define CVT_BS(buf, v0, v1)                                                             \
    {                                                                                   \
        bf16x4 b0 = { (__bf16)v0.x, (__bf16)v0.y, (__bf16)v0.z, (__bf16)v0.w };         \
        bf16x4 b1 = { (__bf16)v1.x, (__bf16)v1.y, (__bf16)v1.z, (__bf16)v1.w };         \
        float f;                                                                        \
        f = (float)b0[0]; sq0 += f * f; f = (float)b0[1]; sq0 += f * f;                 \
        f = (float)b0[2]; sq0 += f * f; f = (float)b0[3]; sq0 += f * f;                 \
        f = (float)b1[0]; sq1 += f * f; f = (float)b1[1]; sq1 += f * f;                 \
        f = (float)b1[2]; sq1 += f * f; f = (float)b1[3]; sq1 += f * f;                 \
        *(bf16x4*)(&Bs[buf][wcol * 32 + kc * 4]) = b0;                                  \
        *(bf16x4*)(&Bs[buf][(wcol + 32) * 32 + kc * 4]) = b1;                           \
    }

    // prologue: tile0 B into LDS, tile0 A via glds, tile1 W into regs
    float4 n0 = *(const float4*)(wp0);
    float4 n1 = *(const float4*)(wp1);
    CVT_BS(0, n0, n1);
    GLDS_TILE(0, 0);
    n0 = *(const float4*)(wp0 + 32);
    n1 = *(const float4*)(wp1 + 32);

    for (int kt = 0; kt < 16; ++kt) {
        const int cur = kt & 1;
        __syncthreads();   // As[cur] glds drained (vmcnt0), Bs[cur] visible
        if (kt < 15) GLDS_TILE(kt + 1, 1 - cur);

        bf16x8 bf[4];
        #pragma unroll
        for (int j = 0; j < 4; ++j)
            bf[j] = *(const bf16x8*)(&Bs[cur][(j * 16 + m16) * 32 + q * 8]);
        #pragma unroll
        for (int i = 0; i < 8; ++i) {
            bf16x8 af = *(const bf16x8*)(&As[cur][(wave * 128 + i * 16 + m16) * 32 + q * 8]);
            #pragma unroll
            for (int j = 0; j < 4; ++j)
                acc[i][j] = __builtin_amdgcn_mfma_f32_16x16x32_bf16(af, bf[j], acc[i][j], 0, 0, 0);
        }

        if (kt < 15) {
            CVT_BS(1 - cur, n0, n1);     // tile kt+1 -> alt buffer
            if (kt < 14) {
                n0 = *(const float4*)(wp0 + (kt + 2) * 32);
                n1 = *(const float4*)(wp1 + (kt + 2) * 32);
            }
        }
    }

    // column sumsq -> csq[64]
    sq0 += __shfl_xor(sq0, 1); sq1 += __shfl_xor(sq1, 1);
    sq0 += __shfl_xor(sq0, 2); sq1 += __shfl_xor(sq1, 2);
    sq0 += __shfl_xor(sq0, 4); sq1 += __shfl_xor(sq1, 4);
    if (kc == 0) { csq[wcol] = sq0; csq[wcol + 32] = sq1; }
    __syncthreads();

    // epilogue: partial sum of exp(S * cosine) per row
    const bool lastb = (cb == LASTB);
    float inv[4]; bool val[4];
    #pragma unroll
    for (int j = 0; j < 4; ++j) {
        int ct = j * 16 + m16;
        val[j] = (!lastb) || (ct < 32);   // last block has 32 valid cols
        inv[j] = rsqrtf(csq[ct]) * S_SCALE;
    }
    #pragma unroll
    for (int i = 0; i < 8; ++i) {
        #pragma unroll
        for (int r = 0; r < 4; ++r) {
            float e = 0.f;
            #pragma unroll
            for (int j = 0; j < 4; ++j)
                if (val[j]) e += __expf(acc[i][j][r] * inv[j]);
            e += __shfl_xor(e, 1);
            e += __shfl_xor(e, 2);
            e += __shfl_xor(e, 4);
            e += __shfl_xor(e, 8);
            if (m16 == 0)
                part[(size_t)cb * BD + wave * 128 + i * 16 + q * 4 + r] = e;
        }
    }
#undef GLDS_TILE
#undef CVT_BS
}

// ---------------- Kernel 3: row logsumexp + label correction + atomic mean ----------------
__global__ __launch_bounds__(256) void k_reduce(const float* __restrict__ part,
                                                const float* __restrict__ sphi,
                                                const float* __restrict__ scos,
                                                float* __restrict__ out) {
    const int b = blockIdx.x;         // 8 blocks x 64 rows
    const int t = threadIdx.x;
    const int r0 = b * 64;
    const int rl = t & 63;
    const int ph = t >> 6;            // 4 cb phases
    float s = 0.f;
    for (int c0 = ph; c0 < NCB; c0 += 4)
        s += part[(size_t)c0 * BD + r0 + rl];
    __shared__ float buf[256];
    buf[t] = s;
    __syncthreads();
    if (t < 64) {
        float total = buf[t] + buf[t + 64] + buf[t + 128] + buf[t + 192];
        int row = r0 + t;
        float lse = logf(total);
        float sp = sphi[row], sc = scos[row];
        float corr = log1pf(__expf(sp - lse) - __expf(sc - lse));
        atomicAdd(out, (lse + corr - sp) * (1.0f / 512.0f));
    }
}

extern "C" void kernel_launch(void* const* d_in, const int* in_sizes, int n_in,
                              void* d_out, int out_size, void* d_ws, size_t ws_size,
                              hipStream_t stream) {
    const float* img  = (const float*)d_in[0];
    const float* prof = (const float*)d_in[1];
    const float* W    = (const float*)d_in[2];
    const int*   lab  = (const int*)d_in[3];

    char* ws = (char*)d_ws;
    __bf16* At   = (__bf16*)ws;                 // 512*512*2 = 524288 B (k-tiled)
    float* sphi  = (float*)(ws + 524288);       // 2048 B
    float* scos  = (float*)(ws + 526336);       // 2048 B
    float* part  = (float*)(ws + 528384);       // 1563*512*4 = 3,201,024 B

    k_prep<<<BD, 256, 0, stream>>>(img, prof, W, lab, At, sphi, scos, (float*)d_out);
    k_gemm<<<NCB, 256, 0, stream>>>(At, W, part);
    k_reduce<<<8, 256, 0, stream>>>(part, sphi, scos, (float*)d_out);
}